// Round 3
// baseline (247.916 us; speedup 1.0000x reference)
//
#include <hip/hip_runtime.h>
#include <cstddef>

// Problem constants (fixed by the reference):
//   B=16, h=8, Ch=32, H=W=56, N=3136
//   heads 0-1  -> 3x3 dwconv (w3,b3), channel base hh*32
//   heads 2-4  -> 5x5 dwconv (w5,b5), channel base hh*32-64
//   heads 5-7  -> 7x7 dwconv (w7,b7), channel base hh*32-160
// out[b][n][hh*32+ch] = q[b][hh][n][ch] * (dwconv(v)[b][hh][n][ch])

#define BH 16
#define NH 8
#define CH 32
#define HW 56
#define NN (HW*HW)

typedef float f32x4 __attribute__((ext_vector_type(4)));
typedef unsigned int u32x4 __attribute__((ext_vector_type(4)));

// Buffer load: hardware bounds check gives conv zero-padding for free.
// OOB (negative voffset as unsigned, or >= num_records) returns 0.
__device__ __forceinline__ f32x4 bload(__amdgpu_buffer_rsrc_t rs, int voff) {
    u32x4 u = __builtin_amdgcn_raw_buffer_load_b128(rs, voff, 0, 0);
    f32x4 f;
    __builtin_memcpy(&f, &u, 16);
    return f;
}

template<int K>
__device__ __forceinline__ void run_head(
    const float* __restrict__ q, const float* __restrict__ v,
    const float* __restrict__ w, const float* __restrict__ bias,
    float* __restrict__ out, int b, int hh, int y0, int cbase,
    float* __restrict__ w_lds)
{
    constexpr int P = K / 2;
    constexpr int NR = 7 + K - 1;      // sliding-window width per dy row
    const int t = threadIdx.x;

    // Stage weights into LDS, layout [tap][c].
    const int nw = K * K * CH;
    for (int i = t; i < nw; i += 128) {
        int tap = i >> 5, c = i & 31;
        w_lds[tap * CH + c] = w[(cbase + c) * (K * K) + tap];
    }
    __syncthreads();

    const int y    = y0 + (t >> 6);    // 2 rows per block, 1 row per wave
    const int lane = t & 63;
    const int xseg = lane >> 3;        // 0..7  -> x0 = xseg*7
    const int chq  = lane & 7;         // 0..7  -> ch = chq*4
    const int x0   = xseg * 7;
    const int ch   = chq * 4;

    const size_t plane = ((size_t)b * NH + hh) * (size_t)NN * CH;
    const float* vb = v + plane;
    const float* qb = q + plane;

    // byte voffsets within a row; negative / >row for halo -> HW OOB -> 0
    int xoff[NR];
#pragma unroll
    for (int j = 0; j < NR; ++j)
        xoff[j] = ((x0 + j - P) * CH + ch) * 4;

    f32x4 bias4 = *(const f32x4*)(bias + cbase + ch);
    f32x4 acc[7];
#pragma unroll
    for (int i = 0; i < 7; ++i) acc[i] = bias4;

    // Per-dy row descriptor (wave-uniform y): OOB rows get num_records=0.
    auto row_rsrc = [&](int dy) {
        const int yy = y + dy - P;
        const bool ok = (unsigned)yy < (unsigned)HW;
        const float* base = vb + (ptrdiff_t)yy * (HW * CH);
        return __builtin_amdgcn_make_buffer_rsrc((void*)base, (short)0,
                                                 ok ? (HW * CH * 4) : 0,
                                                 0x00020000);
    };

    // Software pipeline: double-buffered row windows, loads for dy+1 issued
    // before compute of dy -> compiler emits partial vmcnt waits (overlap).
    f32x4 r[2][NR];
    {
        __amdgpu_buffer_rsrc_t rs = row_rsrc(0);
#pragma unroll
        for (int j = 0; j < NR; ++j) r[0][j] = bload(rs, xoff[j]);
    }
#pragma unroll
    for (int dy = 0; dy < K; ++dy) {
        if (dy + 1 < K) {
            __amdgpu_buffer_rsrc_t rs = row_rsrc(dy + 1);
#pragma unroll
            for (int j = 0; j < NR; ++j) r[(dy + 1) & 1][j] = bload(rs, xoff[j]);
        }
#pragma unroll
        for (int dx = 0; dx < K; ++dx) {
            const f32x4 w4 = *(const f32x4*)(w_lds + (dy * K + dx) * CH + ch);
#pragma unroll
            for (int i = 0; i < 7; ++i)
                acc[i] += r[dy & 1][i + dx] * w4;
        }
    }

    // ev = q * conv_v; write out[b][n][hh*32+ch]
#pragma unroll
    for (int i = 0; i < 7; ++i) {
        const int n = y * HW + x0 + i;
        const f32x4 q4 = *(const f32x4*)(qb + (size_t)n * CH + ch);
        f32x4 o = acc[i] * q4;
        *(f32x4*)(out + ((size_t)b * NN + n) * (NH * CH) + hh * CH + ch) = o;
    }
}

__global__ __launch_bounds__(128)
void clusterformer_fused(const float* __restrict__ q, const float* __restrict__ v,
                         const float* __restrict__ w3, const float* __restrict__ b3,
                         const float* __restrict__ w5, const float* __restrict__ b5,
                         const float* __restrict__ w7, const float* __restrict__ b7,
                         float* __restrict__ out)
{
    __shared__ float w_lds[49 * CH];   // max K=7: 49 taps * 32 ch = 6272 B

    // Heavy-heads-first dispatch order for tail balance:
    //  kk 0..2 -> hh 5,6,7 (K7); kk 3..5 -> hh 2,3,4 (K5); kk 6,7 -> hh 0,1 (K3)
    const int bid = blockIdx.x;
    const int kk  = bid / 448;          // 448 = 16 b * 28 ygroups
    const int rem = bid % 448;
    const int b   = rem / 28;
    const int yg  = rem % 28;
    const int y0  = yg * 2;
    const int hh  = (kk < 3) ? (5 + kk) : ((kk < 6) ? (kk - 1) : (kk - 6));

    if (hh < 2)      run_head<3>(q, v, w3, b3, out, b, hh, y0, hh * 32,       w_lds);
    else if (hh < 5) run_head<5>(q, v, w5, b5, out, b, hh, y0, hh * 32 - 64,  w_lds);
    else             run_head<7>(q, v, w7, b7, out, b, hh, y0, hh * 32 - 160, w_lds);
}

extern "C" void kernel_launch(void* const* d_in, const int* in_sizes, int n_in,
                              void* d_out, int out_size, void* d_ws, size_t ws_size,
                              hipStream_t stream) {
    const float* q  = (const float*)d_in[0];
    const float* v  = (const float*)d_in[1];
    const float* w3 = (const float*)d_in[2];
    const float* b3 = (const float*)d_in[3];
    const float* w5 = (const float*)d_in[4];
    const float* b5 = (const float*)d_in[5];
    const float* w7 = (const float*)d_in[6];
    const float* b7 = (const float*)d_in[7];
    float* out = (float*)d_out;

    const int grid = BH * NH * 28;     // 3584 blocks of 128 threads
    clusterformer_fused<<<grid, 128, 0, stream>>>(q, v, w3, b3, w5, b5, w7, b7, out);
}

// Round 4
// 172.294 us; speedup vs baseline: 1.4389x; 1.4389x over previous
//
#include <hip/hip_runtime.h>
#include <cstddef>

// B=16, h=8, Ch=32, H=W=56, N=3136
//   heads 0-1 -> 3x3 (w3,b3), cbase hh*32
//   heads 2-4 -> 5x5 (w5,b5), cbase hh*32-64
//   heads 5-7 -> 7x7 (w7,b7), cbase hh*32-160
// out[b][n][hh*32+ch] = q[b][hh][n][ch] * dwconv(v)[b][hh][n][ch]

#define BH 16
#define NH 8
#define CH 32
#define HW 56
#define NN (HW*HW)

typedef float f32x4 __attribute__((ext_vector_type(4)));
typedef unsigned int u32x4 __attribute__((ext_vector_type(4)));

// Hardware OOB->0 gives conv zero-padding for free (validated in R2:
// negative voffset as unsigned, or >= num_records, returns 0).
__device__ __forceinline__ f32x4 bload(__amdgpu_buffer_rsrc_t rs, int voff) {
    u32x4 u = __builtin_amdgcn_raw_buffer_load_b128(rs, voff, 0, 0);
    f32x4 f;
    __builtin_memcpy(&f, &u, 16);
    return f;
}

template<int K>
__device__ __forceinline__ void run_head(
    const float* __restrict__ q, const float* __restrict__ v,
    const float* __restrict__ w, const float* __restrict__ bias,
    float* __restrict__ out, int b, int hh, int y0, int cbase,
    float* __restrict__ w_lds)
{
    constexpr int P = K / 2;
    constexpr int NR = 7 + K - 1;      // sliding-window width per dy row
    const int t = threadIdx.x;

    // Stage weights into LDS, layout [tap][c].
    const int nw = K * K * CH;
    for (int i = t; i < nw; i += 256) {
        int tap = i >> 5, c = i & 31;
        w_lds[tap * CH + c] = w[(cbase + c) * (K * K) + tap];
    }
    __syncthreads();

    const int y    = y0 + (t >> 6);    // 4 rows per block, 1 row per wave
    const int lane = t & 63;
    const int xseg = lane >> 3;        // 0..7  -> x0 = xseg*7
    const int chq  = lane & 7;         // 0..7  -> ch = chq*4
    const int x0   = xseg * 7;
    const int ch   = chq * 4;

    const size_t plane = ((size_t)b * NH + hh) * (size_t)NN * CH;
    const float* vb = v + plane;
    const float* qb = q + plane;

    // Per-tap byte voffsets (left halo -> negative -> unsigned-huge -> OOB 0).
    int xoff[NR];
#pragma unroll
    for (int j = 0; j < NR; ++j)
        xoff[j] = ((x0 + j - P) * CH + ch) * 4;

    f32x4 bias4 = *(const f32x4*)(bias + cbase + ch);
    f32x4 acc[7];
#pragma unroll
    for (int i = 0; i < 7; ++i) acc[i] = bias4;

    // SINGLE-buffered row window: 13 quads in flight max (fits the 128-VGPR
    // cap from __launch_bounds__(256,4); R2's double-buffer spilled at 256).
#pragma unroll
    for (int dy = 0; dy < K; ++dy) {
        const int yy = y + dy - P;
        const bool ok = (unsigned)yy < (unsigned)HW;
        const float* base = vb + (ptrdiff_t)yy * (HW * CH);
        __amdgpu_buffer_rsrc_t rs = __builtin_amdgcn_make_buffer_rsrc(
            (void*)base, (short)0, ok ? (HW * CH * 4) : 0, 0x00020000);

        f32x4 r[NR];
#pragma unroll
        for (int j = 0; j < NR; ++j) r[j] = bload(rs, xoff[j]);

#pragma unroll
        for (int dx = 0; dx < K; ++dx) {
            const f32x4 w4 = *(const f32x4*)(w_lds + (dy * K + dx) * CH + ch);
#pragma unroll
            for (int i = 0; i < 7; ++i)
                acc[i] += r[i + dx] * w4;
        }
    }

    // ev = q * conv_v; write out[b][n][hh*32+ch]
#pragma unroll
    for (int i = 0; i < 7; ++i) {
        const int n = y * HW + x0 + i;
        const f32x4 q4 = *(const f32x4*)(qb + (size_t)n * CH + ch);
        f32x4 o = acc[i] * q4;
        *(f32x4*)(out + ((size_t)b * NN + n) * (NH * CH) + hh * CH + ch) = o;
    }
}

__global__ __launch_bounds__(256, 4)   // cap 128 VGPR -> 4 waves/SIMD, no spill
void clusterformer_fused(const float* __restrict__ q, const float* __restrict__ v,
                         const float* __restrict__ w3, const float* __restrict__ b3,
                         const float* __restrict__ w5, const float* __restrict__ b5,
                         const float* __restrict__ w7, const float* __restrict__ b7,
                         float* __restrict__ out)
{
    __shared__ float w_lds[49 * CH];   // max K=7: 6272 B

    // Decode bid -> (plane p, ygroup) with:
    //   * bid % 8 == b % 8  -> all 14 y-blocks of one (b,hh) v-plane (3.2 MB)
    //     land on one XCD's 4 MiB L2 (halo rows L2-hit)
    //   * heavy heads (K7) dispatched first (tail balance)
    const int bid  = blockIdx.x;
    const int p_lo = bid & 7;
    const int t2   = bid >> 3;         // 0..223
    const int p_hi = t2 / 14;
    const int yg   = t2 % 14;
    const int p    = p_hi * 8 + p_lo;  // 0..127
    const int b    = p & 15;
    const int hhp  = p >> 4;           // 0..7, dispatch-ordered head
    const int hh   = (hhp < 3) ? (5 + hhp) : ((hhp < 6) ? (hhp - 1) : (hhp - 6));
    const int y0   = yg * 4;

    if (hh < 2)      run_head<3>(q, v, w3, b3, out, b, hh, y0, hh * 32,       w_lds);
    else if (hh < 5) run_head<5>(q, v, w5, b5, out, b, hh, y0, hh * 32 - 64,  w_lds);
    else             run_head<7>(q, v, w7, b7, out, b, hh, y0, hh * 32 - 160, w_lds);
}

extern "C" void kernel_launch(void* const* d_in, const int* in_sizes, int n_in,
                              void* d_out, int out_size, void* d_ws, size_t ws_size,
                              hipStream_t stream) {
    const float* q  = (const float*)d_in[0];
    const float* v  = (const float*)d_in[1];
    const float* w3 = (const float*)d_in[2];
    const float* b3 = (const float*)d_in[3];
    const float* w5 = (const float*)d_in[4];
    const float* b5 = (const float*)d_in[5];
    const float* w7 = (const float*)d_in[6];
    const float* b7 = (const float*)d_in[7];
    float* out = (float*)d_out;

    const int grid = BH * NH * 14;     // 1792 blocks of 256 threads
    clusterformer_fused<<<grid, 256, 0, stream>>>(q, v, w3, b3, w5, b5, w7, b7, out);
}

// Round 5
// 171.388 us; speedup vs baseline: 1.4465x; 1.0053x over previous
//
#include <hip/hip_runtime.h>
#include <cstddef>

// B=16, h=8, Ch=32, H=W=56, N=3136
//   heads 0-1 -> 3x3 (w3,b3), cbase hh*32
//   heads 2-4 -> 5x5 (w5,b5), cbase hh*32-64
//   heads 5-7 -> 7x7 (w7,b7), cbase hh*32-160
// out[b][n][hh*32+ch] = q[b][hh][n][ch] * dwconv(v)[b][hh][n][ch]

#define BH 16
#define NH 8
#define CH 32
#define HW 56
#define NN (HW*HW)

typedef float f32x4 __attribute__((ext_vector_type(4)));
typedef unsigned int u32x4 __attribute__((ext_vector_type(4)));

// Hardware OOB->0 gives conv zero-padding for free (validated R2/R3:
// negative voffset as unsigned, or >= num_records, returns 0).
__device__ __forceinline__ f32x4 bload(__amdgpu_buffer_rsrc_t rs, int voff) {
    u32x4 u = __builtin_amdgcn_raw_buffer_load_b128(rs, voff, 0, 0);
    f32x4 f;
    __builtin_memcpy(&f, &u, 16);
    return f;
}

template<int K>
__device__ __forceinline__ void run_head(
    const float* __restrict__ q, const float* __restrict__ v,
    const float* __restrict__ w, const float* __restrict__ bias,
    float* __restrict__ out, int b, int hh, int y0, int cbase,
    float* __restrict__ w_lds)
{
    constexpr int P = K / 2;
    constexpr int NR = 7 + K - 1;      // sliding-window width per dy row
    const int t = threadIdx.x;

    // Stage weights into LDS, layout [tap][c].
    const int nw = K * K * CH;
    for (int i = t; i < nw; i += 256) {
        int tap = i >> 5, c = i & 31;
        w_lds[tap * CH + c] = w[(cbase + c) * (K * K) + tap];
    }
    __syncthreads();

    const int y    = y0 + (t >> 6);    // 4 rows per block, 1 row per wave
    const int lane = t & 63;
    const int xseg = lane >> 3;        // 0..7  -> x0 = xseg*7
    const int chq  = lane & 7;         // 0..7  -> ch = chq*4
    const int x0   = xseg * 7;
    const int ch   = chq * 4;

    const size_t plane = ((size_t)b * NH + hh) * (size_t)NN * CH;
    const float* vb = v + plane;
    const float* qb = q + plane;

    // Per-tap byte voffsets (left halo -> negative -> unsigned-huge -> OOB 0).
    int xoff[NR];
#pragma unroll
    for (int j = 0; j < NR; ++j)
        xoff[j] = ((x0 + j - P) * CH + ch) * 4;

    f32x4 bias4 = *(const f32x4*)(bias + cbase + ch);
    f32x4 acc[7];
#pragma unroll
    for (int i = 0; i < 7; ++i) acc[i] = bias4;

#pragma unroll
    for (int dy = 0; dy < K; ++dy) {
        const int yy = y + dy - P;
        const bool ok = (unsigned)yy < (unsigned)HW;
        const float* base = vb + (ptrdiff_t)yy * (HW * CH);
        __amdgpu_buffer_rsrc_t rs = __builtin_amdgcn_make_buffer_rsrc(
            (void*)base, (short)0, ok ? (HW * CH * 4) : 0, 0x00020000);

        f32x4 r[NR];
#pragma unroll
        for (int j = 0; j < NR; ++j) r[j] = bload(rs, xoff[j]);

        // R3 post-mortem: at VGPR=52 the pre-RA scheduler broke this row
        // into ~4-load batches with a vmcnt wait each (latency exposed 4x
        // per dy). Pin ALL NR loads above ALL FMAs -> one vmcnt group,
        // latency exposed once per dy. Forces ~NR*4 VGPRs live (fits the
        // 128 cap from __launch_bounds__(256,4); watch for VGPR~110-128).
        __builtin_amdgcn_sched_barrier(0);

#pragma unroll
        for (int dx = 0; dx < K; ++dx) {
            const f32x4 w4 = *(const f32x4*)(w_lds + (dy * K + dx) * CH + ch);
#pragma unroll
            for (int i = 0; i < 7; ++i)
                acc[i] += r[i + dx] * w4;
        }
    }

    // ev = q * conv_v; write out[b][n][hh*32+ch]
#pragma unroll
    for (int i = 0; i < 7; ++i) {
        const int n = y * HW + x0 + i;
        const f32x4 q4 = *(const f32x4*)(qb + (size_t)n * CH + ch);
        f32x4 o = acc[i] * q4;
        *(f32x4*)(out + ((size_t)b * NN + n) * (NH * CH) + hh * CH + ch) = o;
    }
}

__global__ __launch_bounds__(256, 4)   // cap 128 VGPR -> 4 waves/SIMD
void clusterformer_fused(const float* __restrict__ q, const float* __restrict__ v,
                         const float* __restrict__ w3, const float* __restrict__ b3,
                         const float* __restrict__ w5, const float* __restrict__ b5,
                         const float* __restrict__ w7, const float* __restrict__ b7,
                         float* __restrict__ out)
{
    __shared__ float w_lds[49 * CH];   // max K=7: 6272 B

    // bid -> (plane p, ygroup):
    //   * bid % 8 == const per (b,hh) plane -> one XCD sees a whole 3.2 MB
    //     v-plane (halo rows L2-hit; R3: FETCH 75->53 MB, keep)
    //   * heavy heads (K7) first for tail balance
    const int bid  = blockIdx.x;
    const int p_lo = bid & 7;
    const int t2   = bid >> 3;         // 0..223
    const int p_hi = t2 / 14;
    const int yg   = t2 % 14;
    const int p    = p_hi * 8 + p_lo;  // 0..127
    const int b    = p & 15;
    const int hhp  = p >> 4;           // 0..7, dispatch-ordered head
    const int hh   = (hhp < 3) ? (5 + hhp) : ((hhp < 6) ? (hhp - 1) : (hhp - 6));
    const int y0   = yg * 4;

    if (hh < 2)      run_head<3>(q, v, w3, b3, out, b, hh, y0, hh * 32,       w_lds);
    else if (hh < 5) run_head<5>(q, v, w5, b5, out, b, hh, y0, hh * 32 - 64,  w_lds);
    else             run_head<7>(q, v, w7, b7, out, b, hh, y0, hh * 32 - 160, w_lds);
}

extern "C" void kernel_launch(void* const* d_in, const int* in_sizes, int n_in,
                              void* d_out, int out_size, void* d_ws, size_t ws_size,
                              hipStream_t stream) {
    const float* q  = (const float*)d_in[0];
    const float* v  = (const float*)d_in[1];
    const float* w3 = (const float*)d_in[2];
    const float* b3 = (const float*)d_in[3];
    const float* w5 = (const float*)d_in[4];
    const float* b5 = (const float*)d_in[5];
    const float* w7 = (const float*)d_in[6];
    const float* b7 = (const float*)d_in[7];
    float* out = (float*)d_out;

    const int grid = BH * NH * 14;     // 1792 blocks of 256 threads
    clusterformer_fused<<<grid, 256, 0, stream>>>(q, v, w3, b3, w5, b5, w7, b7, out);
}

// Round 6
// 163.467 us; speedup vs baseline: 1.5166x; 1.0485x over previous
//
#include <hip/hip_runtime.h>
#include <cstddef>

// B=16, h=8, Ch=32, H=W=56, N=3136
//   heads 0-1 -> 3x3 (w3,b3), cbase hh*32
//   heads 2-4 -> 5x5 (w5,b5), cbase hh*32-64
//   heads 5-7 -> 7x7 (w7,b7), cbase hh*32-160
// out[b][n][hh*32+ch] = q[b][hh][n][ch] * dwconv(v)[b][hh][n][ch]
//
// R5 structure: per-wave-private LDS row staging. All global reads are
// contiguous 1-KB wave bursts (lane*16B); conv window is read from LDS.

#define BH 16
#define NH 8
#define CH 32
#define HW 56
#define NN (HW*HW)
#define ROWB (HW*CH*4)          // 7168 B per image row
#define BUF_PX 72               // px slots cover px -8..63 (slot = px+8)
#define BUF_FLOATS (BUF_PX*CH)  // 2304 floats = 9216 B per wave buffer

typedef float f32x4 __attribute__((ext_vector_type(4)));
typedef unsigned int u32x4 __attribute__((ext_vector_type(4)));

__device__ __forceinline__ f32x4 bload(__amdgpu_buffer_rsrc_t rs, int voff) {
    u32x4 u = __builtin_amdgcn_raw_buffer_load_b128(rs, voff, 0, 0);
    f32x4 f; __builtin_memcpy(&f, &u, 16); return f;
}

template<int K>
__device__ __forceinline__ void run_head(
    const float* __restrict__ q, const float* __restrict__ v,
    const float* __restrict__ w, const float* __restrict__ bias,
    float* __restrict__ out, int b, int hh, int y0, int cbase,
    float* __restrict__ w_lds, float* __restrict__ bufs)
{
    constexpr int P = K / 2;
    constexpr int NR = 7 + K - 1;       // window width in px per output strip
    const int t = threadIdx.x;

    // Stage weights into LDS, layout [tap][c].
    const int nw = K * K * CH;
    for (int i = t; i < nw; i += 256) {
        int tap = i >> 5, c = i & 31;
        w_lds[tap * CH + c] = w[(cbase + c) * (K * K) + tap];
    }
    __syncthreads();                    // only barrier in the kernel

    const int wid  = t >> 6;            // wave id = row within 4-row group
    const int lane = t & 63;
    float* wb = bufs + wid * BUF_FLOATS;   // wave-PRIVATE buffer: no barriers

    // Permanent zero x-pads: slots 0..7 (px -8..-1) and 64..71 (px 56..63).
    // Conv zero-padding in x comes from these; they are never overwritten.
    {
        f32x4 z = {0.f, 0.f, 0.f, 0.f};
        *(f32x4*)(wb + lane * 4) = z;             // 1024 B = slots 0..7
        *(f32x4*)(wb + 64 * CH + lane * 4) = z;   // 1024 B = slots 64..71
    }

    const int y    = y0 + wid;
    const int xseg = lane >> 3;         // compute mapping: 8 x-strips
    const int chq  = lane & 7;          //                  8 ch-quads
    const int x0   = xseg * 7;
    const int ch   = chq * 4;

    const size_t plane = ((size_t)b * NH + hh) * (size_t)NN * CH;
    const float* vb   = v + plane;
    const float* qrow = q + plane + (size_t)y * (HW * CH);

    f32x4 bias4 = *(const f32x4*)(bias + cbase + ch);
    f32x4 acc[7];
#pragma unroll
    for (int i = 0; i < 7; ++i) acc[i] = bias4;

#pragma unroll
    for (int dy = 0; dy < K; ++dy) {
        const int yy = y + dy - P;
        const bool ok = (unsigned)yy < (unsigned)HW;
        const float* base = vb + (ptrdiff_t)yy * (HW * CH);
        // OOB row -> num_records=0 -> loads return 0 (y zero-padding, proven R2-R4)
        __amdgpu_buffer_rsrc_t rs = __builtin_amdgcn_make_buffer_rsrc(
            (void*)base, (short)0, ok ? ROWB : 0, 0x00020000);

        // 7 CONTIGUOUS 1-KB wave loads cover the full row (no scatter).
        f32x4 ld[7];
#pragma unroll
        for (int k = 0; k < 7; ++k) ld[k] = bload(rs, k * 1024 + lane * 16);
#pragma unroll
        for (int k = 0; k < 7; ++k)
            *(f32x4*)(wb + (k + 1) * 256 + lane * 4) = ld[k];  // slots 8..63

        // Register window from LDS: one base reg, imm offsets, reused over dx.
        f32x4 r[NR];
        const float* rb = wb + (size_t)(x0 - P + 8) * CH + ch;
#pragma unroll
        for (int j = 0; j < NR; ++j)
            r[j] = *(const f32x4*)(rb + j * CH);

#pragma unroll
        for (int dx = 0; dx < K; ++dx) {
            const f32x4 w4 = *(const f32x4*)(w_lds + (dy * K + dx) * CH + ch);
#pragma unroll
            for (int i = 0; i < 7; ++i)
                acc[i] += r[i + dx] * w4;
        }
    }

    // Epilogue: park conv results in wb to switch lane mapping, so q loads
    // are contiguous 1-KB bursts too; then multiply and store.
#pragma unroll
    for (int i = 0; i < 7; ++i)
        *(f32x4*)(wb + (size_t)(x0 + i + 8) * CH + ch) = acc[i];

    float* orow = out + ((size_t)b * NN + (size_t)y * HW) * (NH * CH) + hh * CH;
    const int px_l = lane >> 3;
    const int chl  = (lane & 7) * 4;
#pragma unroll
    for (int k = 0; k < 7; ++k) {
        const f32x4 c4 = *(const f32x4*)(wb + (size_t)(k * 8 + px_l + 8) * CH + chl);
        const f32x4 q4 = *(const f32x4*)(qrow + k * 256 + lane * 4);  // contiguous
        const f32x4 o  = c4 * q4;
        *(f32x4*)(orow + (size_t)(k * 8 + px_l) * (NH * CH) + chl) = o;
    }
}

__global__ __launch_bounds__(256, 3)   // 43 KB LDS -> 3 blocks/CU, ~170 VGPR cap
void clusterformer_fused(const float* __restrict__ q, const float* __restrict__ v,
                         const float* __restrict__ w3, const float* __restrict__ b3,
                         const float* __restrict__ w5, const float* __restrict__ b5,
                         const float* __restrict__ w7, const float* __restrict__ b7,
                         float* __restrict__ out)
{
    __shared__ __align__(16) float bufs[4 * BUF_FLOATS]; // 36864 B
    __shared__ __align__(16) float w_lds[49 * CH];       // 6272 B

    // bid -> (plane p, ygroup): XCD-local planes (R3: FETCH 75->53 MB) and
    // heavy heads (K7) first for tail balance.
    const int bid  = blockIdx.x;
    const int p_lo = bid & 7;
    const int t2   = bid >> 3;         // 0..223
    const int p_hi = t2 / 14;
    const int yg   = t2 % 14;
    const int p    = p_hi * 8 + p_lo;  // 0..127
    const int b    = p & 15;
    const int hhp  = p >> 4;           // dispatch-ordered head
    const int hh   = (hhp < 3) ? (5 + hhp) : ((hhp < 6) ? (hhp - 1) : (hhp - 6));
    const int y0   = yg * 4;

    if (hh < 2)      run_head<3>(q, v, w3, b3, out, b, hh, y0, hh * 32,       w_lds, bufs);
    else if (hh < 5) run_head<5>(q, v, w5, b5, out, b, hh, y0, hh * 32 - 64,  w_lds, bufs);
    else             run_head<7>(q, v, w7, b7, out, b, hh, y0, hh * 32 - 160, w_lds, bufs);
}

extern "C" void kernel_launch(void* const* d_in, const int* in_sizes, int n_in,
                              void* d_out, int out_size, void* d_ws, size_t ws_size,
                              hipStream_t stream) {
    const float* q  = (const float*)d_in[0];
    const float* v  = (const float*)d_in[1];
    const float* w3 = (const float*)d_in[2];
    const float* b3 = (const float*)d_in[3];
    const float* w5 = (const float*)d_in[4];
    const float* b5 = (const float*)d_in[5];
    const float* w7 = (const float*)d_in[6];
    const float* b7 = (const float*)d_in[7];
    float* out = (float*)d_out;

    const int grid = BH * NH * 14;     // 1792 blocks of 256 threads
    clusterformer_fused<<<grid, 256, 0, stream>>>(q, v, w3, b3, w5, b5, w7, b7, out);
}